// Round 8
// baseline (89.338 us; speedup 1.0000x reference)
//
#include <hip/hip_runtime.h>
#include <hip/hip_bf16.h>

#define NTHREADS 256
#define N_ATOMS  1024
#define HIDDEN   64
#define SEGCAP   272     // per-wave queue: 256 max survivors + 16 pad

// One block per atom (B*N = 8192 blocks), 256 threads.
//  phase 1a: upfront vectorized loads (3x float4 + int4 per thread); 4
//    ballot rounds; per-wave queue segments with wave-uniform running base
//    (NO atomics, no broadcast); entries are sign-packed (d, +/-cutv);
//    segments zero-padded to x16.
//  phase 1b: divergence-free drain, thread = (slot p = tid>>4, rbf r =
//    tid&15); ONE ds_read_b64 + ONE exp per entry feeds BOTH species
//    accumulators; shfl_xor(16,32) combine; per-wave partials to LDS.
//  phase 2: proven R2/R6 MLP tail -- block-wide barriers between layers
//    (executed by ALL threads; barrier-free wave-sync variant NaN'd in R7).
__global__ __launch_bounds__(NTHREADS) void LocalFeatureEncoder_40063454937486_kernel(
    const float* __restrict__ pos,    // [B,N,3]
    const int*   __restrict__ types,  // [B,N]
    const float* __restrict__ W1,     // [34,64]
    const float* __restrict__ b1,     // [64]
    const float* __restrict__ W2,     // [64,64]
    const float* __restrict__ b2,     // [64]
    const float* __restrict__ W3,     // [64,64]
    const float* __restrict__ b3,     // [64]
    float*       __restrict__ out)    // [B,N,64]
{
    const int a    = blockIdx.x;          // b*N + i
    const int bidx = a >> 10;             // N = 1024
    const int i    = a & (N_ATOMS - 1);
    const int tid  = threadIdx.x;
    const int lane = tid & 63;
    const int wav  = tid >> 6;

    __shared__ float2 qdm[4 * SEGCAP];    // per-wave (d, cutv*typesign) queues
    __shared__ float2 part2[4 * 16];      // per-wave env partials (acc0, acc1)
    __shared__ int    nseg[4];            // padded per-wave survivor counts
    __shared__ float  feats[64];          // 34 used
    __shared__ float  h1s[64];
    __shared__ float  h2s[64];

    const float* pf   = pos + (size_t)bidx * (N_ATOMS * 3);
    const int*   typb = types + (size_t)bidx * N_ATOMS;

    // ---- issue all neighbor loads up front (latency overlap) ----
    const float4 p0 = *(const float4*)(pf + tid * 12);
    const float4 p1 = *(const float4*)(pf + tid * 12 + 4);
    const float4 p2 = *(const float4*)(pf + tid * 12 + 8);
    const int4   tv = *(const int4*)(typb + tid * 4);

    const float xi = pf[i * 3 + 0];
    const float yi = pf[i * 3 + 1];
    const float zi = pf[i * 3 + 2];

    // ---------- phase 1a: distances + per-wave compaction (no atomics) ----------
    {
        const float px[4] = {p0.x, p0.w, p1.z, p2.y};
        const float py[4] = {p0.y, p1.x, p1.w, p2.z};
        const float pz[4] = {p0.z, p1.y, p2.x, p2.w};
        const int   tj[4] = {tv.x, tv.y, tv.z, tv.w};
        float2* seg = &qdm[wav * SEGCAP];
        int base = 0;                        // wave-uniform running count

#pragma unroll
        for (int q = 0; q < 4; ++q) {
            const int j = tid * 4 + q;
            const float dx = xi - px[q], dy = yi - py[q], dz = zi - pz[q];
            const float sq = dx * dx + dy * dy + dz * dz;
            const bool pred = (j != i) && (sq < 6.25f);

            const unsigned long long mask = __ballot(pred);
            if (pred) {
                const float d  = sqrtf(sq);
                const float x  = d * 0.4f;       // d / 2.5
                const float x3 = x * x * x;
                const float cutv = 1.0f + x3 * (-10.0f + x * (15.0f - 6.0f * x));
                const int idx = base + (int)__popcll(mask & ((1ull << lane) - 1ull));
                seg[idx] = make_float2(d, (tj[q] == 0) ? cutv : -cutv);
            }
            base += (int)__popcll(mask);     // wave-uniform: no shfl needed
        }
        // zero-pad to a multiple of 16 -> divergence-free drain
        const int npad = (base + 15) & ~15;
        if (lane < npad - base) seg[base + lane] = make_float2(0.0f, 0.0f);
        if (lane == 0) nseg[wav] = npad;
    }
    __syncthreads();

    // ---------- phase 1b: 16-slot x 16-rbf drain, both species per lane ----------
    {
        const int   p = tid >> 4;            // block-wide slot 0..15
        const int   r = tid & 15;            // rbf this lane owns
        const float c = (float)r * (2.5f / 15.0f);

        float acc0 = 0.0f, acc1 = 0.0f;
#pragma unroll
        for (int w = 0; w < 4; ++w) {
            const int n = nseg[w];
            const float2* s = &qdm[w * SEGCAP];
            for (int e = p; e < n; e += 16) {
                const float2 dm  = s[e];
                const float diff = dm.x - c;
                const float ex   = __expf(diff * diff * -36.0f);  // 1/w^2 = 36
                acc0 += ex * fmaxf(dm.y, 0.0f);
                acc1 += ex * fmaxf(-dm.y, 0.0f);
            }
        }
        // combine the 4 slots within this wave: lanes r, r+16, r+32, r+48
        acc0 += __shfl_xor(acc0, 16, 64);
        acc0 += __shfl_xor(acc0, 32, 64);
        acc1 += __shfl_xor(acc1, 16, 64);
        acc1 += __shfl_xor(acc1, 32, 64);
        if (lane < 16) part2[wav * 16 + lane] = make_float2(acc0, acc1);
    }
    __syncthreads();

    // ---------- combine partials into feats ----------
    if (tid < 16) {
        const float2 a0 = part2[tid];
        const float2 a1 = part2[16 + tid];
        const float2 a2 = part2[32 + tid];
        const float2 a3 = part2[48 + tid];
        feats[2 + 2 * tid + 0] = a0.x + a1.x + a2.x + a3.x;
        feats[2 + 2 * tid + 1] = a0.y + a1.y + a2.y + a3.y;
    }
    if (tid == 16) {
        const int ti = typb[i];
        feats[0] = (ti == 0) ? 1.0f : 0.0f;
        feats[1] = (ti == 1) ? 1.0f : 0.0f;
    }
    __syncthreads();

    // ---------- phase 2: MLP (threads 0..63), block-wide barriers ----------
    if (tid < HIDDEN) {
        float h = b1[tid];
#pragma unroll
        for (int k = 0; k < 34; k++) h += feats[k] * W1[k * HIDDEN + tid];
        h = h / (1.0f + __expf(-h));
        h1s[tid] = h;
    }
    __syncthreads();
    if (tid < HIDDEN) {
        float h = b2[tid];
#pragma unroll
        for (int k = 0; k < HIDDEN; k++) h += h1s[k] * W2[k * HIDDEN + tid];
        h = h / (1.0f + __expf(-h));
        h2s[tid] = h;
    }
    __syncthreads();
    if (tid < HIDDEN) {
        float o = b3[tid];
#pragma unroll
        for (int k = 0; k < HIDDEN; k++) o += h2s[k] * W3[k * HIDDEN + tid];
        out[(size_t)a * HIDDEN + tid] = o;
    }
}

extern "C" void kernel_launch(void* const* d_in, const int* in_sizes, int n_in,
                              void* d_out, int out_size, void* d_ws, size_t ws_size,
                              hipStream_t stream) {
    const float* pos   = (const float*)d_in[0];
    const int*   types = (const int*)d_in[1];
    const float* W1    = (const float*)d_in[2];
    const float* b1    = (const float*)d_in[3];
    const float* W2    = (const float*)d_in[4];
    const float* b2    = (const float*)d_in[5];
    const float* W3    = (const float*)d_in[6];
    const float* b3    = (const float*)d_in[7];
    float*       out   = (float*)d_out;

    const int BN = in_sizes[1];           // B*N = 8192

    LocalFeatureEncoder_40063454937486_kernel<<<BN, NTHREADS, 0, stream>>>(
        pos, types, W1, b1, W2, b2, W3, b3, out);
}

// Round 9
// 89.277 us; speedup vs baseline: 1.0007x; 1.0007x over previous
//
#include <hip/hip_runtime.h>
#include <hip/hip_bf16.h>

#define NTHREADS 256
#define N_ATOMS  1024
#define HIDDEN   64
#define SEGCAP   512     // per-wave queue entries (expected ~65, pad x4)

// 4 atoms per block (B*N/4 = 2048 blocks), one WAVE per atom.
//  - stage all 1024 neighbors into LDS SoA (x,y,z,tsign) once per block,
//    reused by all 4 atoms (4x less global traffic, 4x fewer blocks).
//  - per wave: 16 sweeps over LDS neighbors; ballot-compact survivors as
//    sign-packed +/-d (4 B/entry; cutv recomputed in drain) into a
//    per-wave LDS queue, wave-uniform running base (no atomics); pad to
//    x4 with d=100 (exp underflows to exactly 0, cutv finite).
//  - drain: lane = (slot 0..3, rbf 0..15), one ds_read_b32 + one exp per
//    entry feeds both species accumulators; shfl_xor(16,32) combine.
//  - MLP: shuffle-broadcast (R3-proven correct), all 64 lanes of ALL 4
//    waves concurrently, zero LDS, zero extra barriers.
// Only 2 block-wide barriers total.
__global__ __launch_bounds__(NTHREADS) void LocalFeatureEncoder_40063454937486_kernel(
    const float* __restrict__ pos,    // [B,N,3]
    const int*   __restrict__ types,  // [B,N]
    const float* __restrict__ W1,     // [34,64]
    const float* __restrict__ b1,     // [64]
    const float* __restrict__ W2,     // [64,64]
    const float* __restrict__ b2,     // [64]
    const float* __restrict__ W3,     // [64,64]
    const float* __restrict__ b3,     // [64]
    float*       __restrict__ out)    // [B,N,64]
{
    const int tid  = threadIdx.x;
    const int lane = tid & 63;
    const int wav  = tid >> 6;
    const int a    = blockIdx.x * 4 + wav;   // this wave's atom (b*N + i)
    const int bidx = blockIdx.x >> 8;        // 256 blocks per batch
    const int i    = a & (N_ATOMS - 1);

    __shared__ float sx[N_ATOMS];
    __shared__ float sy[N_ATOMS];
    __shared__ float sz[N_ATOMS];
    __shared__ float st[N_ATOMS];            // +1.0 (type 0) / -1.0 (type 1)
    __shared__ float qv[4 * SEGCAP];         // per-wave sign-packed +/-d

    const float* pf   = pos + (size_t)bidx * (N_ATOMS * 3);
    const int*   typb = types + (size_t)bidx * N_ATOMS;

    // ---- stage all 1024 neighbors into LDS SoA (once per block) ----
    {
        const float4 p0 = *(const float4*)(pf + tid * 12);
        const float4 p1 = *(const float4*)(pf + tid * 12 + 4);
        const float4 p2 = *(const float4*)(pf + tid * 12 + 8);
        const int4   tv = *(const int4*)(typb + tid * 4);

        const float px[4] = {p0.x, p0.w, p1.z, p2.y};
        const float py[4] = {p0.y, p1.x, p1.w, p2.z};
        const float pz[4] = {p0.z, p1.y, p2.x, p2.w};
        const int   tj[4] = {tv.x, tv.y, tv.z, tv.w};
#pragma unroll
        for (int q = 0; q < 4; ++q) {
            const int j = tid * 4 + q;
            sx[j] = px[q];
            sy[j] = py[q];
            sz[j] = pz[q];
            st[j] = (tj[q] == 0) ? 1.0f : -1.0f;
        }
    }
    __syncthreads();

    const float xi = sx[i];
    const float yi = sy[i];
    const float zi = sz[i];

    // ---- sweeps + per-wave compaction (sign-packed +/-d) ----
    float* seg = &qv[wav * SEGCAP];
    int base = 0;                            // wave-uniform running count
#pragma unroll
    for (int s = 0; s < N_ATOMS / 64; ++s) {
        const int j = lane + s * 64;
        const float dx = xi - sx[j];
        const float dy = yi - sy[j];
        const float dz = zi - sz[j];
        const float sq = dx * dx + dy * dy + dz * dz;
        const bool pred = (j != i) && (sq < 6.25f);

        const unsigned long long mask = __ballot(pred);
        if (pred) {
            const float d = sqrtf(sq);
            const int idx = base + (int)__popcll(mask & ((1ull << lane) - 1ull));
            seg[idx] = (st[j] > 0.0f) ? d : -d;  // sign encodes species
        }
        base += (int)__popcll(mask);
    }
    // pad to a multiple of 4 with d=100 (zero contribution, finite cutv)
    const int npad = (base + 3) & ~3;
    if (lane < npad - base) seg[base + lane] = 100.0f;
    __syncthreads();                         // queue visible (safe ordering)

    // ---- drain: lane = (slot p = lane>>4, rbf r = lane&15) ----
    float acc0 = 0.0f, acc1 = 0.0f;
    {
        const int   p = lane >> 4;           // NOTE: 4 slots => stride 4
        const int   r = lane & 15;
        const float c = (float)r * (2.5f / 15.0f);
        const int   slot = p;                // 0..3
        for (int e = slot; e < npad; e += 4) {
            const float v   = seg[e];
            const float d   = fabsf(v);
            const float sgn = __builtin_copysignf(1.0f, v);
            const float x   = d * 0.4f;      // d / 2.5
            const float x3  = x * x * x;
            const float cutv = 1.0f + x3 * (-10.0f + x * (15.0f - 6.0f * x));
            const float diff = d - c;
            const float ex   = __expf(diff * diff * -36.0f);  // 1/w^2 = 36
            const float m0 = (sgn > 0.0f) ? cutv : 0.0f;
            const float m1 = (sgn > 0.0f) ? 0.0f : cutv;
            acc0 += ex * m0;
            acc1 += ex * m1;
        }
    }
    // combine the 4 slots: lanes r, r+16, r+32, r+48
    acc0 += __shfl_xor(acc0, 16, 64);
    acc0 += __shfl_xor(acc0, 32, 64);
    acc1 += __shfl_xor(acc1, 16, 64);
    acc1 += __shfl_xor(acc1, 32, 64);
    // every lane in {r, r+16, r+32, r+48} now holds full env[r][0/1]

    // ---- MLP 34 -> 64 -> 64 -> 64, shuffle-broadcast, all 64 lanes ----
    const int t  = lane;                     // output unit this lane owns
    const int ti = (st[i] < 0.0f) ? 1 : 0;   // own atom type (wave-uniform)

    float h1 = b1[t] + W1[ti * HIDDEN + t];  // onehot contribution
#pragma unroll
    for (int r = 0; r < 16; ++r) {
        h1 += __shfl(acc0, r, 64) * W1[(2 + 2 * r + 0) * HIDDEN + t];
        h1 += __shfl(acc1, r, 64) * W1[(2 + 2 * r + 1) * HIDDEN + t];
    }
    h1 = h1 / (1.0f + __expf(-h1));

    float h2 = b2[t];
#pragma unroll
    for (int k = 0; k < HIDDEN; ++k) {
        h2 += __shfl(h1, k, 64) * W2[k * HIDDEN + t];
    }
    h2 = h2 / (1.0f + __expf(-h2));

    float o = b3[t];
#pragma unroll
    for (int k = 0; k < HIDDEN; ++k) {
        o += __shfl(h2, k, 64) * W3[k * HIDDEN + t];
    }
    out[(size_t)a * HIDDEN + t] = o;
}

extern "C" void kernel_launch(void* const* d_in, const int* in_sizes, int n_in,
                              void* d_out, int out_size, void* d_ws, size_t ws_size,
                              hipStream_t stream) {
    const float* pos   = (const float*)d_in[0];
    const int*   types = (const int*)d_in[1];
    const float* W1    = (const float*)d_in[2];
    const float* b1    = (const float*)d_in[3];
    const float* W2    = (const float*)d_in[4];
    const float* b2    = (const float*)d_in[5];
    const float* W3    = (const float*)d_in[6];
    const float* b3    = (const float*)d_in[7];
    float*       out   = (float*)d_out;

    const int BN = in_sizes[1];              // B*N = 8192

    LocalFeatureEncoder_40063454937486_kernel<<<BN / 4, NTHREADS, 0, stream>>>(
        pos, types, W1, b1, W2, b2, W3, b3, out);
}